// Round 12
// baseline (92.687 us; speedup 1.0000x reference)
//
#include <hip/hip_runtime.h>

#define FEAT   256
#define K2     512      // 2*FEAT
#define NNODES 100000
#define BATCH  50000
#define NS     10
#define EMBED  256
#define BN     32
#define NBLK   ((BATCH + BN - 1) / BN)   // 1563
#define FCONV_BLKS (NNODES * FEAT / 8 / 256)   // 12500
#define WPACK_BLKS 64

typedef __attribute__((ext_vector_type(8))) __bf16         bf16x8;
typedef __attribute__((ext_vector_type(8))) unsigned short ushort8;
typedef __attribute__((ext_vector_type(4))) float          f32x4;
typedef __attribute__((ext_vector_type(2))) float          f32x2;
typedef __attribute__((ext_vector_type(2))) int            i32x2;
typedef __attribute__((ext_vector_type(4))) int            i32x4;

static __device__ __forceinline__ unsigned short f2bf(float x) {
    unsigned int u = __builtin_bit_cast(unsigned int, x);
    u += 0x7FFFu + ((u >> 16) & 1u);
    return (unsigned short)(u >> 16);
}

static __device__ __forceinline__ void wpack_body(int c, const float* __restrict__ w,
                                                  unsigned short* __restrict__ wp) {
    int lane = c & 63;
    int ks   = (c >> 6) & 1;
    int mblk = (c >> 7) & 15;
    int kt   = c >> 11;
    int row  = mblk * 16 + (lane & 15);
    int col  = kt * 64 + ks * 32 + (lane >> 4) * 8;
    const f32x4* src = (const f32x4*)(w + row * K2 + col);
    f32x4 a = src[0], b = src[1];
    ushort8 h;
    h[0]=f2bf(a[0]); h[1]=f2bf(a[1]); h[2]=f2bf(a[2]); h[3]=f2bf(a[3]);
    h[4]=f2bf(b[0]); h[5]=f2bf(b[1]); h[6]=f2bf(b[2]); h[7]=f2bf(b[3]);
    ((ushort8*)wp)[c] = h;
}

// ---- merged prep: features f32 -> fp8 table (keeps features hot in L3)
//      + weight f32 -> bf16 fragment-major pack ----
__global__ void prep_kernel(const float* __restrict__ f,
                            unsigned char* __restrict__ f8,
                            const float* __restrict__ w,
                            unsigned short* __restrict__ wp) {
    const int bid = blockIdx.x;
    if (bid < FCONV_BLKS) {
        int i = bid * 256 + threadIdx.x;   // one 8-elem chunk
        const f32x4* src = (const f32x4*)(f + (size_t)i * 8);
        f32x4 a = src[0], b = src[1];
        int u0 = 0, u1 = 0;
        u0 = __builtin_amdgcn_cvt_pk_fp8_f32(a[0], a[1], u0, false);
        u0 = __builtin_amdgcn_cvt_pk_fp8_f32(a[2], a[3], u0, true);
        u1 = __builtin_amdgcn_cvt_pk_fp8_f32(b[0], b[1], u1, false);
        u1 = __builtin_amdgcn_cvt_pk_fp8_f32(b[2], b[3], u1, true);
        i32x2 p; p[0] = u0; p[1] = u1;
        ((i32x2*)f8)[i] = p;
    } else {
        wpack_body((bid - FCONV_BLKS) * 256 + threadIdx.x, w, wp);
    }
}

// ---- standalone weight pack (fallback tier) ----
__global__ void wpack_kernel(const float* __restrict__ w,
                             unsigned short* __restrict__ wp) {
    wpack_body(blockIdx.x * 256 + threadIdx.x, w, wp);
}

// ---- fused BN=32: self f32 (L3-hot) + neighbor fp8, MFMA, relu ----
// LDS lB[32][512] bf16, XOR swizzle: 8-col chunk index low3 ^= (row&7)
// launch_bounds(512,6): 3 blocks/CU resident -> gather/MFMA cross-block overlap
__global__ __launch_bounds__(512, 6) void gemm_hyb(
    const float* __restrict__ features,
    const unsigned char* __restrict__ f8,
    const unsigned short* __restrict__ wp,
    const int* __restrict__ nodes,
    const int* __restrict__ neigh,
    float* __restrict__ out) {

    __shared__ __align__(16) unsigned short lB[BN * K2];   // 32 KB

    const int tid = threadIdx.x;
    const int nb0 = blockIdx.x * BN;
    const int r   = tid >> 4;     // 0..31 row in tile
    const int p   = tid & 15;     // 16-col span
    const int rx  = r & 7;
    const int n   = min(nb0 + r, BATCH - 1);   // clamp; store is guarded

    // ---- self half: f32 row direct (L3-hot after prep) ----
    {
        const int node0 = nodes[n];
        const f32x4* s0 = (const f32x4*)(features + (size_t)node0 * FEAT + p * 16);
        f32x4 x0 = s0[0], x1 = s0[1], x2 = s0[2], x3 = s0[3];
        ushort8 a, b;
        a[0]=f2bf(x0[0]); a[1]=f2bf(x0[1]); a[2]=f2bf(x0[2]); a[3]=f2bf(x0[3]);
        a[4]=f2bf(x1[0]); a[5]=f2bf(x1[1]); a[6]=f2bf(x1[2]); a[7]=f2bf(x1[3]);
        b[0]=f2bf(x2[0]); b[1]=f2bf(x2[1]); b[2]=f2bf(x2[2]); b[3]=f2bf(x2[3]);
        b[4]=f2bf(x3[0]); b[5]=f2bf(x3[1]); b[6]=f2bf(x3[2]); b[7]=f2bf(x3[3]);
        const int g = p >> 2, i0 = (p & 3) * 2;
        unsigned short* dst = lB + r * K2 + g * 64;
        *(ushort8*)&dst[((i0    ) ^ rx) * 8] = a;
        *(ushort8*)&dst[((i0 + 1) ^ rx) * 8] = b;
    }

    // ---- neighbor half: fp8 rows (256 B), one 16 B piece per thread per sample ----
    {
        int idx[NS];
        #pragma unroll
        for (int s = 0; s < NS; ++s) idx[s] = neigh[n * NS + s];

        float acc[16];
        #pragma unroll
        for (int e = 0; e < 16; ++e) acc[e] = 0.f;

        #pragma unroll
        for (int s = 0; s < NS; ++s) {
            i32x4 v = *(const i32x4*)(f8 + (size_t)idx[s] * FEAT + p * 16);
            #pragma unroll
            for (int q = 0; q < 4; ++q) {
                f32x2 lo = __builtin_amdgcn_cvt_pk_f32_fp8(v[q], false);
                f32x2 hi = __builtin_amdgcn_cvt_pk_f32_fp8(v[q], true);
                acc[q * 4 + 0] += lo[0];
                acc[q * 4 + 1] += lo[1];
                acc[q * 4 + 2] += hi[0];
                acc[q * 4 + 3] += hi[1];
            }
        }
        ushort8 a, b;
        #pragma unroll
        for (int e = 0; e < 8; ++e) {
            a[e] = f2bf(acc[e]     * 0.1f);
            b[e] = f2bf(acc[8 + e] * 0.1f);
        }
        const int g = 4 + (p >> 2), i0 = (p & 3) * 2;
        unsigned short* dst = lB + r * K2 + g * 64;
        *(ushort8*)&dst[((i0    ) ^ rx) * 8] = a;
        *(ushort8*)&dst[((i0 + 1) ^ rx) * 8] = b;
    }

    // ---- hoist kt=0 weight fragments above the barrier (starts L2 stream early) ----
    const int w    = tid >> 6;
    const int lane = tid & 63;
    bf16x8 af0[2][2];
    #pragma unroll
    for (int i = 0; i < 2; ++i)
        #pragma unroll
        for (int ks = 0; ks < 2; ++ks)
            af0[i][ks] = *(const bf16x8*)(wp +
                ((((w * 2 + i) * 2 + ks) * 64 + lane) << 3));
    __syncthreads();

    // ---- MFMA: 8 waves, wave w -> m rows [w*32, w*32+32), all 32 n-cols ----
    const int lr = lane & 15;
    const int lg = lane >> 4;

    f32x4 facc[2][2] = {};

    #pragma unroll
    for (int kt = 0; kt < 8; ++kt) {
        bf16x8 af[2][2], bfr[2][2];
        #pragma unroll
        for (int i = 0; i < 2; ++i)
            #pragma unroll
            for (int ks = 0; ks < 2; ++ks)
                af[i][ks] = (kt == 0) ? af0[i][ks]
                    : *(const bf16x8*)(wp +
                        ((((kt * 16 + w * 2 + i) * 2 + ks) * 64 + lane) << 3));
        #pragma unroll
        for (int j = 0; j < 2; ++j) {
            const int rb = j * 16 + lr;
            #pragma unroll
            for (int ks = 0; ks < 2; ++ks) {
                int cc = kt * 8 + ((ks * 4 + lg) ^ (rb & 7));
                bfr[j][ks] = *(const bf16x8*)&lB[rb * K2 + cc * 8];
            }
        }
        #pragma unroll
        for (int ks = 0; ks < 2; ++ks)
            #pragma unroll
            for (int i = 0; i < 2; ++i)
                #pragma unroll
                for (int j = 0; j < 2; ++j)
                    facc[i][j] = __builtin_amdgcn_mfma_f32_16x16x32_bf16(
                        af[i][ks], bfr[j][ks], facc[i][j], 0, 0, 0);
    }

    // ---- epilogue: relu + nt store. C/D: col=lane&15, row=(lane>>4)*4+reg ----
    #pragma unroll
    for (int j = 0; j < 2; ++j) {
        const int n2 = nb0 + j * 16 + lr;
        if (n2 < BATCH) {
            #pragma unroll
            for (int i = 0; i < 2; ++i) {
                int m0 = w * 32 + i * 16 + lg * 4;
                #pragma unroll
                for (int rg = 0; rg < 4; ++rg) {
                    float v = facc[i][j][rg];
                    v = v > 0.f ? v : 0.f;
                    __builtin_nontemporal_store(v, &out[(size_t)(m0 + rg) * BATCH + n2]);
                }
            }
        }
    }
}

// ---- fallback (ws too small): all-f32 gather ----
__global__ __launch_bounds__(512, 4) void gemm_f32(
    const float* __restrict__ features,
    const unsigned short* __restrict__ wp,
    const int* __restrict__ nodes,
    const int* __restrict__ neigh,
    float* __restrict__ out) {

    __shared__ __align__(16) unsigned short lB[BN * K2];

    const int tid = threadIdx.x;
    const int nb0 = blockIdx.x * BN;
    const int r  = tid >> 4;
    const int h  = tid & 15;
    const int rx = r & 7;
    const int n  = min(nb0 + r, BATCH - 1);

    int node0 = nodes[n];
    int nidx[NS];
    #pragma unroll
    for (int s = 0; s < NS; ++s) nidx[s] = neigh[n * NS + s];

    {
        const f32x4* s0 = (const f32x4*)(features + (size_t)node0 * FEAT + h * 16);
        f32x4 x0 = s0[0], x1 = s0[1], x2 = s0[2], x3 = s0[3];
        ushort8 a, b;
        a[0]=f2bf(x0[0]); a[1]=f2bf(x0[1]); a[2]=f2bf(x0[2]); a[3]=f2bf(x0[3]);
        a[4]=f2bf(x1[0]); a[5]=f2bf(x1[1]); a[6]=f2bf(x1[2]); a[7]=f2bf(x1[3]);
        b[0]=f2bf(x2[0]); b[1]=f2bf(x2[1]); b[2]=f2bf(x2[2]); b[3]=f2bf(x2[3]);
        b[4]=f2bf(x3[0]); b[5]=f2bf(x3[1]); b[6]=f2bf(x3[2]); b[7]=f2bf(x3[3]);
        const int g = h >> 2, i0 = (h & 3) * 2;
        unsigned short* dst = lB + r * K2 + g * 64;
        *(ushort8*)&dst[((i0    ) ^ rx) * 8] = a;
        *(ushort8*)&dst[((i0 + 1) ^ rx) * 8] = b;
    }
    {
        float acc[16];
        #pragma unroll
        for (int e = 0; e < 16; ++e) acc[e] = 0.f;
        #pragma unroll
        for (int s = 0; s < NS; ++s) {
            const f32x4* pp = (const f32x4*)(features + (size_t)nidx[s] * FEAT + h * 16);
            f32x4 x0 = pp[0], x1 = pp[1], x2 = pp[2], x3 = pp[3];
            #pragma unroll
            for (int e = 0; e < 4; ++e) {
                acc[e]      += x0[e];
                acc[4 + e]  += x1[e];
                acc[8 + e]  += x2[e];
                acc[12 + e] += x3[e];
            }
        }
        ushort8 aa, bb;
        #pragma unroll
        for (int e = 0; e < 8; ++e) {
            aa[e] = f2bf(acc[e]     * 0.1f);
            bb[e] = f2bf(acc[8 + e] * 0.1f);
        }
        const int g = 4 + (h >> 2), i0 = (h & 3) * 2;
        unsigned short* dst = lB + r * K2 + g * 64;
        *(ushort8*)&dst[((i0    ) ^ rx) * 8] = aa;
        *(ushort8*)&dst[((i0 + 1) ^ rx) * 8] = bb;
    }
    __syncthreads();

    const int w    = tid >> 6;
    const int lane = tid & 63;
    const int lr   = lane & 15;
    const int lg   = lane >> 4;

    f32x4 facc[2][2] = {};
    #pragma unroll
    for (int kt = 0; kt < 8; ++kt) {
        bf16x8 af[2][2], bfr[2][2];
        #pragma unroll
        for (int i = 0; i < 2; ++i)
            #pragma unroll
            for (int ks = 0; ks < 2; ++ks)
                af[i][ks] = *(const bf16x8*)(wp +
                    ((((kt * 16 + w * 2 + i) * 2 + ks) * 64 + lane) << 3));
        #pragma unroll
        for (int j = 0; j < 2; ++j) {
            const int rb = j * 16 + lr;
            #pragma unroll
            for (int ks = 0; ks < 2; ++ks) {
                int cc = kt * 8 + ((ks * 4 + lg) ^ (rb & 7));
                bfr[j][ks] = *(const bf16x8*)&lB[rb * K2 + cc * 8];
            }
        }
        #pragma unroll
        for (int ks = 0; ks < 2; ++ks)
            #pragma unroll
            for (int i = 0; i < 2; ++i)
                #pragma unroll
                for (int j = 0; j < 2; ++j)
                    facc[i][j] = __builtin_amdgcn_mfma_f32_16x16x32_bf16(
                        af[i][ks], bfr[j][ks], facc[i][j], 0, 0, 0);
    }
    #pragma unroll
    for (int j = 0; j < 2; ++j) {
        const int n2 = nb0 + j * 16 + lr;
        if (n2 < BATCH) {
            #pragma unroll
            for (int i = 0; i < 2; ++i) {
                int m0 = w * 32 + i * 16 + lg * 4;
                #pragma unroll
                for (int rg = 0; rg < 4; ++rg) {
                    float v = facc[i][j][rg];
                    v = v > 0.f ? v : 0.f;
                    __builtin_nontemporal_store(v, &out[(size_t)(m0 + rg) * BATCH + n2]);
                }
            }
        }
    }
}

extern "C" void kernel_launch(void* const* d_in, const int* in_sizes, int n_in,
                              void* d_out, int out_size, void* d_ws, size_t ws_size,
                              hipStream_t stream) {
    const float* features = (const float*)d_in[0];
    const float* weight   = (const float*)d_in[1];
    const int*   nodes    = (const int*)d_in[2];
    const int*   neigh    = (const int*)d_in[3];
    float* out = (float*)d_out;

    unsigned short* wp = (unsigned short*)d_ws;                 // 256 KB packed weight
    unsigned char*  f8 = (unsigned char*)(wp + (size_t)EMBED * K2); // 25.6 MB fp8 table

    const size_t need = (size_t)EMBED * K2 * 2 + (size_t)NNODES * FEAT;

    if (ws_size >= need) {
        prep_kernel<<<FCONV_BLKS + WPACK_BLKS, 256, 0, stream>>>(features, f8, weight, wp);
        gemm_hyb<<<NBLK, 512, 0, stream>>>(features, f8, wp, nodes, neigh, out);
    } else {
        wpack_kernel<<<WPACK_BLKS, 256, 0, stream>>>(weight, wp);
        gemm_f32<<<NBLK, 512, 0, stream>>>(features, wp, nodes, neigh, out);
    }
}

// Round 13
// 69.795 us; speedup vs baseline: 1.3280x; 1.3280x over previous
//
#include <hip/hip_runtime.h>

#define FEAT   256
#define K2     512      // 2*FEAT
#define NNODES 100000
#define BATCH  50000
#define NS     10
#define EMBED  256
#define BN     32
#define NBLK   ((BATCH + BN - 1) / BN)   // 1563
#define FCONV_BLKS (NNODES * FEAT / 8 / 256)   // 12500
#define WPACK_BLKS 64

typedef __attribute__((ext_vector_type(8))) __bf16         bf16x8;
typedef __attribute__((ext_vector_type(8))) unsigned short ushort8;
typedef __attribute__((ext_vector_type(4))) float          f32x4;
typedef __attribute__((ext_vector_type(2))) float          f32x2;
typedef __attribute__((ext_vector_type(2))) int            i32x2;
typedef __attribute__((ext_vector_type(4))) int            i32x4;

static __device__ __forceinline__ unsigned short f2bf(float x) {
    unsigned int u = __builtin_bit_cast(unsigned int, x);
    u += 0x7FFFu + ((u >> 16) & 1u);
    return (unsigned short)(u >> 16);
}

static __device__ __forceinline__ void wpack_body(int c, const float* __restrict__ w,
                                                  unsigned short* __restrict__ wp) {
    int lane = c & 63;
    int ks   = (c >> 6) & 1;
    int mblk = (c >> 7) & 15;
    int kt   = c >> 11;
    int row  = mblk * 16 + (lane & 15);
    int col  = kt * 64 + ks * 32 + (lane >> 4) * 8;
    const f32x4* src = (const f32x4*)(w + row * K2 + col);
    f32x4 a = src[0], b = src[1];
    ushort8 h;
    h[0]=f2bf(a[0]); h[1]=f2bf(a[1]); h[2]=f2bf(a[2]); h[3]=f2bf(a[3]);
    h[4]=f2bf(b[0]); h[5]=f2bf(b[1]); h[6]=f2bf(b[2]); h[7]=f2bf(b[3]);
    ((ushort8*)wp)[c] = h;
}

// ---- merged prep: features f32 -> fp8 table (keeps features hot in L3)
//      + weight f32 -> bf16 fragment-major pack ----
__global__ void prep_kernel(const float* __restrict__ f,
                            unsigned char* __restrict__ f8,
                            const float* __restrict__ w,
                            unsigned short* __restrict__ wp) {
    const int bid = blockIdx.x;
    if (bid < FCONV_BLKS) {
        int i = bid * 256 + threadIdx.x;   // one 8-elem chunk
        const f32x4* src = (const f32x4*)(f + (size_t)i * 8);
        f32x4 a = src[0], b = src[1];
        int u0 = 0, u1 = 0;
        u0 = __builtin_amdgcn_cvt_pk_fp8_f32(a[0], a[1], u0, false);
        u0 = __builtin_amdgcn_cvt_pk_fp8_f32(a[2], a[3], u0, true);
        u1 = __builtin_amdgcn_cvt_pk_fp8_f32(b[0], b[1], u1, false);
        u1 = __builtin_amdgcn_cvt_pk_fp8_f32(b[2], b[3], u1, true);
        i32x2 p; p[0] = u0; p[1] = u1;
        ((i32x2*)f8)[i] = p;
    } else {
        wpack_body((bid - FCONV_BLKS) * 256 + threadIdx.x, w, wp);
    }
}

// ---- standalone weight pack (fallback tier) ----
__global__ void wpack_kernel(const float* __restrict__ w,
                             unsigned short* __restrict__ wp) {
    wpack_body(blockIdx.x * 256 + threadIdx.x, w, wp);
}

// ---- fused BN=32: self f32 (L3-hot) + neighbor fp8, MFMA, relu,
//      full-line epilogue via in-LDS transpose (kills partial-line RFO) ----
// LDS lB[32][512] bf16, XOR swizzle: 8-col chunk index low3 ^= (row&7)
__global__ __launch_bounds__(512, 4) void gemm_hyb(
    const float* __restrict__ features,
    const unsigned char* __restrict__ f8,
    const unsigned short* __restrict__ wp,
    const int* __restrict__ nodes,
    const int* __restrict__ neigh,
    float* __restrict__ out) {

    __shared__ __align__(16) unsigned short lB[BN * K2];   // 32 KB

    const int tid = threadIdx.x;
    const int nb0 = blockIdx.x * BN;
    const int r   = tid >> 4;     // 0..31 row in tile
    const int p   = tid & 15;     // 16-col span
    const int rx  = r & 7;
    const int n   = min(nb0 + r, BATCH - 1);   // clamp; store is guarded

    // ---- self half: f32 row direct (L3-hot after prep) ----
    {
        const int node0 = nodes[n];
        const f32x4* s0 = (const f32x4*)(features + (size_t)node0 * FEAT + p * 16);
        f32x4 x0 = s0[0], x1 = s0[1], x2 = s0[2], x3 = s0[3];
        ushort8 a, b;
        a[0]=f2bf(x0[0]); a[1]=f2bf(x0[1]); a[2]=f2bf(x0[2]); a[3]=f2bf(x0[3]);
        a[4]=f2bf(x1[0]); a[5]=f2bf(x1[1]); a[6]=f2bf(x1[2]); a[7]=f2bf(x1[3]);
        b[0]=f2bf(x2[0]); b[1]=f2bf(x2[1]); b[2]=f2bf(x2[2]); b[3]=f2bf(x2[3]);
        b[4]=f2bf(x3[0]); b[5]=f2bf(x3[1]); b[6]=f2bf(x3[2]); b[7]=f2bf(x3[3]);
        const int g = p >> 2, i0 = (p & 3) * 2;
        unsigned short* dst = lB + r * K2 + g * 64;
        *(ushort8*)&dst[((i0    ) ^ rx) * 8] = a;
        *(ushort8*)&dst[((i0 + 1) ^ rx) * 8] = b;
    }

    // ---- neighbor half: fp8 rows (256 B), one 16 B piece per thread per sample ----
    {
        int idx[NS];
        #pragma unroll
        for (int s = 0; s < NS; ++s) idx[s] = neigh[n * NS + s];

        float acc[16];
        #pragma unroll
        for (int e = 0; e < 16; ++e) acc[e] = 0.f;

        #pragma unroll
        for (int s = 0; s < NS; ++s) {
            i32x4 v = *(const i32x4*)(f8 + (size_t)idx[s] * FEAT + p * 16);
            #pragma unroll
            for (int q = 0; q < 4; ++q) {
                f32x2 lo = __builtin_amdgcn_cvt_pk_f32_fp8(v[q], false);
                f32x2 hi = __builtin_amdgcn_cvt_pk_f32_fp8(v[q], true);
                acc[q * 4 + 0] += lo[0];
                acc[q * 4 + 1] += lo[1];
                acc[q * 4 + 2] += hi[0];
                acc[q * 4 + 3] += hi[1];
            }
        }
        ushort8 a, b;
        #pragma unroll
        for (int e = 0; e < 8; ++e) {
            a[e] = f2bf(acc[e]     * 0.1f);
            b[e] = f2bf(acc[8 + e] * 0.1f);
        }
        const int g = 4 + (p >> 2), i0 = (p & 3) * 2;
        unsigned short* dst = lB + r * K2 + g * 64;
        *(ushort8*)&dst[((i0    ) ^ rx) * 8] = a;
        *(ushort8*)&dst[((i0 + 1) ^ rx) * 8] = b;
    }
    __syncthreads();

    // ---- MFMA: 8 waves, wave w -> m rows [w*32, w*32+32), all 32 n-cols ----
    const int w    = tid >> 6;
    const int lane = tid & 63;
    const int lr   = lane & 15;
    const int lg   = lane >> 4;

    f32x4 facc[2][2] = {};

    #pragma unroll
    for (int kt = 0; kt < 8; ++kt) {
        bf16x8 af[2][2], bfr[2][2];
        #pragma unroll
        for (int i = 0; i < 2; ++i)
            #pragma unroll
            for (int ks = 0; ks < 2; ++ks)
                af[i][ks] = *(const bf16x8*)(wp +
                    ((((kt * 16 + w * 2 + i) * 2 + ks) * 64 + lane) << 3));
        #pragma unroll
        for (int j = 0; j < 2; ++j) {
            const int rb = j * 16 + lr;
            #pragma unroll
            for (int ks = 0; ks < 2; ++ks) {
                int cc = kt * 8 + ((ks * 4 + lg) ^ (rb & 7));
                bfr[j][ks] = *(const bf16x8*)&lB[rb * K2 + cc * 8];
            }
        }
        #pragma unroll
        for (int ks = 0; ks < 2; ++ks)
            #pragma unroll
            for (int i = 0; i < 2; ++i)
                #pragma unroll
                for (int j = 0; j < 2; ++j)
                    facc[i][j] = __builtin_amdgcn_mfma_f32_16x16x32_bf16(
                        af[i][ks], bfr[j][ks], facc[i][j], 0, 0, 0);
    }

    // ---- epilogue: transpose 32x32 tile in own 4KB LDS slice, store FULL lines ----
    // C/D layout: col(n) = lane&15, row(m) = (lane>>4)*4 + reg
    __syncthreads();                         // all waves done reading lB
    float* T = (float*)lB + w * 1024;        // 32x32 f32, col swizzle n' = n ^ (((m>>2)&3)<<3)
    #pragma unroll
    for (int i = 0; i < 2; ++i)
        #pragma unroll
        for (int j = 0; j < 2; ++j)
            #pragma unroll
            for (int rg = 0; rg < 4; ++rg) {
                int ml = i * 16 + lg * 4 + rg;
                int nl = j * 16 + lr;
                T[ml * 32 + (nl ^ (((ml >> 2) & 3) << 3))] = facc[i][j][rg];
            }
    // wave-internal: ds_writes above ordered before reads below via lgkmcnt
    #pragma unroll
    for (int pr = 0; pr < 16; ++pr) {
        const int ml = pr * 2 + (lane >> 5);
        const int nl = lane & 31;
        float v = T[ml * 32 + (nl ^ (((ml >> 2) & 3) << 3))];
        v = v > 0.f ? v : 0.f;
        const int n2 = nb0 + nl;
        if (n2 < BATCH)
            __builtin_nontemporal_store(v, &out[(size_t)(w * 32 + ml) * BATCH + n2]);
    }
}

// ---- fallback (ws too small): all-f32 gather ----
__global__ __launch_bounds__(512, 4) void gemm_f32(
    const float* __restrict__ features,
    const unsigned short* __restrict__ wp,
    const int* __restrict__ nodes,
    const int* __restrict__ neigh,
    float* __restrict__ out) {

    __shared__ __align__(16) unsigned short lB[BN * K2];

    const int tid = threadIdx.x;
    const int nb0 = blockIdx.x * BN;
    const int r  = tid >> 4;
    const int h  = tid & 15;
    const int rx = r & 7;
    const int n  = min(nb0 + r, BATCH - 1);

    int node0 = nodes[n];
    int nidx[NS];
    #pragma unroll
    for (int s = 0; s < NS; ++s) nidx[s] = neigh[n * NS + s];

    {
        const f32x4* s0 = (const f32x4*)(features + (size_t)node0 * FEAT + h * 16);
        f32x4 x0 = s0[0], x1 = s0[1], x2 = s0[2], x3 = s0[3];
        ushort8 a, b;
        a[0]=f2bf(x0[0]); a[1]=f2bf(x0[1]); a[2]=f2bf(x0[2]); a[3]=f2bf(x0[3]);
        a[4]=f2bf(x1[0]); a[5]=f2bf(x1[1]); a[6]=f2bf(x1[2]); a[7]=f2bf(x1[3]);
        b[0]=f2bf(x2[0]); b[1]=f2bf(x2[1]); b[2]=f2bf(x2[2]); b[3]=f2bf(x2[3]);
        b[4]=f2bf(x3[0]); b[5]=f2bf(x3[1]); b[6]=f2bf(x3[2]); b[7]=f2bf(x3[3]);
        const int g = h >> 2, i0 = (h & 3) * 2;
        unsigned short* dst = lB + r * K2 + g * 64;
        *(ushort8*)&dst[((i0    ) ^ rx) * 8] = a;
        *(ushort8*)&dst[((i0 + 1) ^ rx) * 8] = b;
    }
    {
        float acc[16];
        #pragma unroll
        for (int e = 0; e < 16; ++e) acc[e] = 0.f;
        #pragma unroll
        for (int s = 0; s < NS; ++s) {
            const f32x4* pp = (const f32x4*)(features + (size_t)nidx[s] * FEAT + h * 16);
            f32x4 x0 = pp[0], x1 = pp[1], x2 = pp[2], x3 = pp[3];
            #pragma unroll
            for (int e = 0; e < 4; ++e) {
                acc[e]      += x0[e];
                acc[4 + e]  += x1[e];
                acc[8 + e]  += x2[e];
                acc[12 + e] += x3[e];
            }
        }
        ushort8 aa, bb;
        #pragma unroll
        for (int e = 0; e < 8; ++e) {
            aa[e] = f2bf(acc[e]     * 0.1f);
            bb[e] = f2bf(acc[8 + e] * 0.1f);
        }
        const int g = 4 + (h >> 2), i0 = (h & 3) * 2;
        unsigned short* dst = lB + r * K2 + g * 64;
        *(ushort8*)&dst[((i0    ) ^ rx) * 8] = aa;
        *(ushort8*)&dst[((i0 + 1) ^ rx) * 8] = bb;
    }
    __syncthreads();

    const int w    = tid >> 6;
    const int lane = tid & 63;
    const int lr   = lane & 15;
    const int lg   = lane >> 4;

    f32x4 facc[2][2] = {};
    #pragma unroll
    for (int kt = 0; kt < 8; ++kt) {
        bf16x8 af[2][2], bfr[2][2];
        #pragma unroll
        for (int i = 0; i < 2; ++i)
            #pragma unroll
            for (int ks = 0; ks < 2; ++ks)
                af[i][ks] = *(const bf16x8*)(wp +
                    ((((kt * 16 + w * 2 + i) * 2 + ks) * 64 + lane) << 3));
        #pragma unroll
        for (int j = 0; j < 2; ++j) {
            const int rb = j * 16 + lr;
            #pragma unroll
            for (int ks = 0; ks < 2; ++ks) {
                int cc = kt * 8 + ((ks * 4 + lg) ^ (rb & 7));
                bfr[j][ks] = *(const bf16x8*)&lB[rb * K2 + cc * 8];
            }
        }
        #pragma unroll
        for (int ks = 0; ks < 2; ++ks)
            #pragma unroll
            for (int i = 0; i < 2; ++i)
                #pragma unroll
                for (int j = 0; j < 2; ++j)
                    facc[i][j] = __builtin_amdgcn_mfma_f32_16x16x32_bf16(
                        af[i][ks], bfr[j][ks], facc[i][j], 0, 0, 0);
    }
    #pragma unroll
    for (int j = 0; j < 2; ++j) {
        const int n2 = nb0 + j * 16 + lr;
        if (n2 < BATCH) {
            #pragma unroll
            for (int i = 0; i < 2; ++i) {
                int m0 = w * 32 + i * 16 + lg * 4;
                #pragma unroll
                for (int rg = 0; rg < 4; ++rg) {
                    float v = facc[i][j][rg];
                    v = v > 0.f ? v : 0.f;
                    __builtin_nontemporal_store(v, &out[(size_t)(m0 + rg) * BATCH + n2]);
                }
            }
        }
    }
}

extern "C" void kernel_launch(void* const* d_in, const int* in_sizes, int n_in,
                              void* d_out, int out_size, void* d_ws, size_t ws_size,
                              hipStream_t stream) {
    const float* features = (const float*)d_in[0];
    const float* weight   = (const float*)d_in[1];
    const int*   nodes    = (const int*)d_in[2];
    const int*   neigh    = (const int*)d_in[3];
    float* out = (float*)d_out;

    unsigned short* wp = (unsigned short*)d_ws;                 // 256 KB packed weight
    unsigned char*  f8 = (unsigned char*)(wp + (size_t)EMBED * K2); // 25.6 MB fp8 table

    const size_t need = (size_t)EMBED * K2 * 2 + (size_t)NNODES * FEAT;

    if (ws_size >= need) {
        prep_kernel<<<FCONV_BLKS + WPACK_BLKS, 256, 0, stream>>>(features, f8, weight, wp);
        gemm_hyb<<<NBLK, 512, 0, stream>>>(features, f8, wp, nodes, neigh, out);
    } else {
        wpack_kernel<<<WPACK_BLKS, 256, 0, stream>>>(weight, wp);
        gemm_f32<<<NBLK, 512, 0, stream>>>(features, wp, nodes, neigh, out);
    }
}